// Round 17
// baseline (7730.563 us; speedup 1.0000x reference)
//
#include <hip/hip_runtime.h>

// Problem constants
#define Bn 4
#define Ln 256
#define Dn 256
#define Wn 8
#define BLD (Bn*Ln*Dn)   // 262144
#define BDD (Bn*Dn*Dn)   // 262144

typedef float  floatx4 __attribute__((ext_vector_type(4)));
typedef short  short8  __attribute__((ext_vector_type(8)));

// bf16 pack (RNE)
__device__ __forceinline__ unsigned f2bf(float x) {
    unsigned u = __float_as_uint(x);
    return (u + 0x7FFFu + ((u >> 16) & 1u)) >> 16;
}
__device__ __forceinline__ unsigned long long packbf4(floatx4 v) {
    unsigned lo = f2bf(v[0]) | (f2bf(v[1]) << 16);
    unsigned hi = f2bf(v[2]) | (f2bf(v[3]) << 16);
    return (unsigned long long)lo | ((unsigned long long)hi << 32);
}
union BF8 { short8 s8; unsigned long long u[2]; };

// -------------------------------------------------------------------------
// kphi + gamma    [verified round 2]
// -------------------------------------------------------------------------
__global__ __launch_bounds__(256) void kphi_gamma_kernel(
    const float* __restrict__ k_al, const float* __restrict__ x,
    const float* __restrict__ poly, const float* __restrict__ gW,
    const float* __restrict__ gb, float* __restrict__ kphi,
    float* __restrict__ gamma)
{
    int wg = blockIdx.x, tid = threadIdx.x;
    int wave = tid >> 6, lane = tid & 63;
    int n = wg * 4 + wave;
    float gacc = 0.f;
#pragma unroll
    for (int c = 0; c < 4; ++c) {
        int e = lane + 64 * c;
        float kv = k_al[n * Dn + e];
        kphi[n * Dn + e] = poly[e] * kv + poly[Dn + e] * kv * kv;
        gacc += x[n * Dn + e] * gW[e];
    }
#pragma unroll
    for (int off = 32; off; off >>= 1) gacc += __shfl_xor(gacc, off);
    if (lane == 0) gamma[n] = 1.f / (1.f + expf(-(gacc + gb[0])));
}

// -------------------------------------------------------------------------
// tiled GEMM  [verified round 2]
// -------------------------------------------------------------------------
template <int ACT>
__global__ __launch_bounds__(256) void gemm_act_kernel(
    const float* __restrict__ In, const float* __restrict__ Wm,
    const float* __restrict__ bias, float* __restrict__ Out)
{
    __shared__ float ldsX[32 * 64];
    __shared__ float ldsW[64 * 65];
    int n0 = blockIdx.x * 32;
    int m0 = blockIdx.y * 64;
    int tid = threadIdx.x;
    float acc[8] = {0, 0, 0, 0, 0, 0, 0, 0};
    for (int j0 = 0; j0 < 256; j0 += 64) {
#pragma unroll
        for (int q = 0; q < 2; ++q) {
            int fi = tid + 256 * q; int row = fi >> 4; int c4 = (fi & 15) << 2;
            *(float4*)&ldsX[row * 64 + c4] =
                *(const float4*)&In[(n0 + row) * 256 + j0 + c4];
        }
#pragma unroll
        for (int q = 0; q < 4; ++q) {
            int fi = tid + 256 * q; int row = fi >> 4; int c4 = (fi & 15) << 2;
            float4 vv = *(const float4*)&Wm[(m0 + row) * 256 + j0 + c4];
            ldsW[(c4 + 0) * 65 + row] = vv.x;
            ldsW[(c4 + 1) * 65 + row] = vv.y;
            ldsW[(c4 + 2) * 65 + row] = vv.z;
            ldsW[(c4 + 3) * 65 + row] = vv.w;
        }
        __syncthreads();
        int m = tid & 63, ng = tid >> 6;
        for (int j = 0; j < 64; ++j) {
            float wv = ldsW[j * 65 + m];
#pragma unroll
            for (int r = 0; r < 8; ++r) acc[r] += ldsX[(ng * 8 + r) * 64 + j] * wv;
        }
        __syncthreads();
    }
    int m = tid & 63, ng = tid >> 6;
    float bv = bias[m0 + m];
#pragma unroll
    for (int r = 0; r < 8; ++r) {
        float vv = acc[r] + bv;
        if (ACT == 1) vv = 1.f / (1.f + expf(-vv));
        if (ACT == 2) vv = 0.1f / (1.f + expf(-vv));
        Out[(n0 + ng * 8 + r) * 256 + m0 + m] = vv;
    }
}

// -------------------------------------------------------------------------
// K-gram precompute   [verified round 8]
// -------------------------------------------------------------------------
__global__ __launch_bounds__(64) void kgram_kernel(
    const float* __restrict__ kphi, float* __restrict__ Kall)
{
    int t = blockIdx.x, b = blockIdx.y, tid = threadIdx.x;
    int wa = tid >> 3, wb = tid & 7;
    int ta = t - 7 + wa, tb = t - 7 + wb;
    float g = 0.f;
    if (ta >= 0 && tb >= 0) {
        const float* pa = &kphi[(b * Ln + ta) * Dn];
        const float* pb = &kphi[(b * Ln + tb) * Dn];
        for (int j = 0; j < Dn; j += 4) {
            floatx4 x1 = *(const floatx4*)&pa[j];
            floatx4 x2 = *(const floatx4*)&pb[j];
            g += x1[0]*x2[0] + x1[1]*x2[1] + x1[2]*x2[2] + x1[3]*x2[3];
        }
    }
    Kall[(b * Ln + t) * 64 + tid] = g;
}

// -------------------------------------------------------------------------
// prologue: M_prev -> outM, S_prev -> S parity0 (= outS); zero ys, errp
// -------------------------------------------------------------------------
__global__ __launch_bounds__(256) void prologue_kernel(
    const float* __restrict__ Mprev, const float* __restrict__ Sprev,
    float* __restrict__ M, float* __restrict__ S0,
    float* __restrict__ ys, float* __restrict__ errp)
{
    int gidx = blockIdx.x * 256 + threadIdx.x;   // 0..65535
    ((float4*)M)[gidx] = ((const float4*)Mprev)[gidx];
    ((float4*)S0)[gidx] = ((const float4*)Sprev)[gidx];
    float4 z = {0.f, 0.f, 0.f, 0.f};
    ((float4*)ys)[gidx] = z;
    if (gidx < 16384) ((float4*)errp)[gidx] = z;   // 65536 floats (both parities)
}

// -------------------------------------------------------------------------
// T init: Tg0 = Sprev Sprev^T (bf16 MFMA)    [verified round 16]
// -------------------------------------------------------------------------
__global__ __launch_bounds__(256) void tinit_kernel(
    const float* __restrict__ Sprev, float* __restrict__ Tg0)
{
    const int wg = blockIdx.x, tid = threadIdx.x;
    const int b = wg >> 4, rem = wg & 15;
    const int i0 = (rem >> 2) * 64, l0 = (rem & 3) * 64;
    const int wid = tid >> 6, lane = tid & 63;
    const int lme = lane & 15, hi = lane >> 4;
    floatx4 acc[4];
#pragma unroll
    for (int lt = 0; lt < 4; ++lt) acc[lt] = (floatx4){0.f,0.f,0.f,0.f};
#pragma unroll
    for (int kc = 0; kc < 8; ++kc) {
        int kb2 = kc*32 + hi*8;
        floatx4 a0 = *(const floatx4*)&Sprev[(size_t)(b*256 + i0 + wid*16 + lme)*256 + kb2];
        floatx4 a1 = *(const floatx4*)&Sprev[(size_t)(b*256 + i0 + wid*16 + lme)*256 + kb2 + 4];
        BF8 ua; ua.u[0] = packbf4(a0); ua.u[1] = packbf4(a1);
#pragma unroll
        for (int lt = 0; lt < 4; ++lt) {
            int brow = l0 + lt*16 + lme;
            floatx4 b0 = *(const floatx4*)&Sprev[(size_t)(b*256 + brow)*256 + kb2];
            floatx4 b1 = *(const floatx4*)&Sprev[(size_t)(b*256 + brow)*256 + kb2 + 4];
            BF8 ub; ub.u[0] = packbf4(b0); ub.u[1] = packbf4(b1);
            acc[lt] = __builtin_amdgcn_mfma_f32_16x16x32_bf16(ua.s8, ub.s8, acc[lt], 0,0,0);
        }
    }
#pragma unroll
    for (int lt = 0; lt < 4; ++lt)
#pragma unroll
        for (int g = 0; g < 4; ++g)
            Tg0[(size_t)(b*256 + i0 + wid*16 + (hi<<2) + g)*256 + l0 + lt*16 + lme]
                = acc[lt][g];
}

// -------------------------------------------------------------------------
// err0 + rowsq0: errp parity-0 for t=0, rowsq parity-0 = ||S_prev rows||^2
// -------------------------------------------------------------------------
__global__ __launch_bounds__(256) void err0_kernel(
    const float* __restrict__ kphi, const float* __restrict__ Mprev,
    const float* __restrict__ Sprev, float* __restrict__ errp,
    float* __restrict__ rowsq0)
{
    __shared__ float kW2[Wn * 256];
    const int wg = blockIdx.x, tid = threadIdx.x;
    const int b = wg >> 4, rem = wg & 15;
    const int s = rem & 3;
    const int i0 = (rem >> 2) * 64, l0 = (rem & 3) * 64;
    const int wid = tid >> 6, lane = tid & 63;
    const int lme = lane & 15, hi = lane >> 4;
    const int ibr = i0 + wid * 16 + (hi << 2);
#pragma unroll
    for (int q = 0; q < 2; ++q) {
        int w = q*4 + (tid >> 6);
        int c4 = (tid & 63) << 2;
        floatx4 kv = {0.f,0.f,0.f,0.f};
        if (w == 7) kv = *(const floatx4*)&kphi[(size_t)(b*Ln)*Dn + c4];
        *(floatx4*)&kW2[w*256 + c4] = kv;
    }
    __syncthreads();
    float M_reg[16];
#pragma unroll
    for (int lt = 0; lt < 4; ++lt)
#pragma unroll
        for (int g = 0; g < 4; ++g)
            M_reg[lt*4+g] = Mprev[(size_t)(b*256 + ibr + g)*256 + l0 + lt*16 + lme];
#pragma unroll
    for (int w = 0; w < 8; ++w) {
        float pd[4] = {0.f,0.f,0.f,0.f};
#pragma unroll
        for (int lt = 0; lt < 4; ++lt) {
            float kv2 = kW2[w*256 + l0 + lt*16 + lme];
#pragma unroll
            for (int g = 0; g < 4; ++g) pd[g] += M_reg[lt*4+g] * kv2;
        }
#pragma unroll
        for (int g = 0; g < 4; ++g) {
            pd[g] += __shfl_xor(pd[g], 1); pd[g] += __shfl_xor(pd[g], 2);
            pd[g] += __shfl_xor(pd[g], 4); pd[g] += __shfl_xor(pd[g], 8);
        }
        if (lme == 0)
#pragma unroll
            for (int g = 0; g < 4; ++g)
                errp[(size_t)((s*2 + 0)*4 + b)*2048 + w*256 + ibr + g] = pd[g];
    }
    if (rem == 0) {
        // rowsq0[b][tid] = ||S_prev[b][tid][:]||^2
        const float* Srow = &Sprev[(size_t)(b*256 + tid)*256];
        float sq = 0.f;
        for (int j = 0; j < 256; j += 4) {
            floatx4 sv = *(const floatx4*)&Srow[j];
            sq += sv[0]*sv[0] + sv[1]*sv[1] + sv[2]*sv[2] + sv[3]*sv[3];
        }
        rowsq0[b*256 + tid] = sq;
    }
}

// -------------------------------------------------------------------------
// STEP kernel (one per t). Block (b, rem): tile (i0,l0) + strip d0.
// Zero same-step cross-block deps: u/q/c/S_new-cols/norm recomputed locally;
// all cross-step state parity-double-buffered through the kernel boundary.
// -------------------------------------------------------------------------
#define OFF_STB   0        // bf16 [64][264] swizzled S_new^T panel (8448 fl)
#define OFF_UV    8448     // [8][256]
#define OFF_QV    10496    // [8][256]
#define OFF_CV    12544    // [8][256]
#define OFF_TH    14592    // [256]
#define OFF_KWA   14848    // [8][260]
#define OFF_KW2   16928    // [8][256]
#define OFF_KL    18976    // [64]
#define OFF_RED   19040    // [16]
#define SMEM_FL   19056    // 76.2 KB

__global__ __launch_bounds__(256) void step_kernel(
    const float* __restrict__ kphi, const float* __restrict__ vin,
    const float* __restrict__ gammaB, const float* __restrict__ alphaB,
    const float* __restrict__ etaB, const float* __restrict__ thetaB,
    const float* __restrict__ Kall,
    const float* __restrict__ S_in, float* __restrict__ S_out,
    const float* __restrict__ Tin, float* __restrict__ Tout,
    const float* __restrict__ rowsq_in, float* __restrict__ rowsq_out,
    float* __restrict__ errp, float* __restrict__ Mg, float* __restrict__ ys,
    int t)
{
    __shared__ float smem[SMEM_FL];
    char*  STb = (char*)(smem + OFF_STB);
    float* uv  = smem + OFF_UV;
    float* qv  = smem + OFF_QV;
    float* cv  = smem + OFF_CV;
    float* thv = smem + OFF_TH;
    float* kWA = smem + OFF_KWA;
    float* kW2 = smem + OFF_KW2;
    float* Kl  = smem + OFF_KL;
    float* red = smem + OFF_RED;

    const int wg = blockIdx.x, tid = threadIdx.x;
    const int b = wg >> 4, rem = wg & 15;
    const int s = rem & 3;
    const int i0 = (rem >> 2) * 64, l0 = (rem & 3) * 64;
    const int d0 = rem << 4;
    const int wid = tid >> 6, lane = tid & 63;
    const int lme = lane & 15, hi = lane >> 4;
    const int ibr = i0 + wid * 16 + (hi << 2);
    const int r = tid >> 4, m = tid & 15;
    const int e0 = m * 16;
    const int cwin = (t + 1 < Wn) ? (t + 1) : Wn;
    const float invc = 1.f / (float)cwin;
    const int p = t & 1;

    // ---- stage: kWA(window t), kW2(window t+1), theta, Kl ; u vector
#pragma unroll
    for (int qq = 0; qq < 2; ++qq) {
        int idx = qq*256 + tid;
        int w = idx >> 6, c4 = (idx & 63) * 4;
        int tk = t - 7 + w;
        floatx4 kv = {0,0,0,0};
        if (tk >= 0) kv = *(const floatx4*)&kphi[(size_t)(b*Ln + tk)*Dn + c4];
        *(floatx4*)&kWA[w*260 + c4] = kv;
        floatx4 kv2 = {0,0,0,0};
        int tk2 = t + 1 - 7 + w;
        if (t + 1 < Ln && tk2 >= 0)
            kv2 = *(const floatx4*)&kphi[(size_t)(b*Ln + tk2)*Dn + c4];
        *(floatx4*)&kW2[w*256 + c4] = kv2;
    }
    if (tid < 64)
        *(floatx4*)&thv[tid*4] = *(const floatx4*)&thetaB[(size_t)(b*Ln + t)*Dn + tid*4];
    if (tid < 16)
        *(floatx4*)&Kl[tid*4] = *(const floatx4*)&Kall[(size_t)(b*Ln + t)*64 + tid*4];
    // u[w][d=tid]
    {
#pragma unroll
        for (int w = 0; w < 8; ++w) {
            float ep = 0.f;
#pragma unroll
            for (int sl = 0; sl < 4; ++sl)
                ep += errp[(size_t)((sl*2 + p)*4 + b)*2048 + w*256 + tid];
            int tok = t - 7 + w;
            float uu = 0.f;
            if (tok >= 0)
                uu = gammaB[b*Ln + tok] * invc *
                     (ep - vin[(size_t)(b*Ln + tok)*Dn + tid]);
            uv[w*256 + tid] = uu;
        }
    }
    __syncthreads();

    // ---- q[w][d=tid] = S_in[d,:] . k_w  (full, redundant per block)
    {
        const float* Srow = &S_in[(size_t)(b*256 + tid)*256];
        float qw[8] = {0,0,0,0,0,0,0,0};
        for (int j = 0; j < 256; j += 4) {
            floatx4 sv = *(const floatx4*)&Srow[j];
#pragma unroll
            for (int w = 0; w < 8; ++w) {
                floatx4 kv = *(const floatx4*)&kWA[w*260 + j];
                qw[w] += sv[0]*kv[0] + sv[1]*kv[1] + sv[2]*kv[2] + sv[3]*kv[3];
            }
        }
#pragma unroll
        for (int w = 0; w < 8; ++w) qv[w*256 + tid] = qw[w];
    }

    // ---- strip S_new rows d0..d0+15 -> S_out (round-9 A-role math)
    {
        float th_r = thetaB[(size_t)(b*Ln + t)*Dn + d0 + r];
        float uu8[8];
#pragma unroll
        for (int w = 0; w < 8; ++w) uu8[w] = uv[w*256 + d0 + r];
#pragma unroll
        for (int cq = 0; cq < 4; ++cq) {
            floatx4 sv = *(const floatx4*)&S_in[(size_t)(b*256 + d0 + r)*256 + e0 + cq*4];
            sv = th_r * sv;
#pragma unroll
            for (int w = 0; w < 8; ++w) {
                floatx4 kv = *(const floatx4*)&kWA[w*260 + e0 + cq*4];
                sv += uu8[w] * kv;
            }
            *(floatx4*)&S_out[(size_t)(b*256 + d0 + r)*256 + e0 + cq*4] = sv;
        }
    }

    // ---- l0-column S_new -> bf16 STb panel (local; same formula, fp32)
    float uL[8];
#pragma unroll
    for (int w = 0; w < 8; ++w) uL[w] = uv[w*256 + tid];
    {
        float th_d = thv[tid];
        for (int j0 = 0; j0 < 64; j0 += 4) {
            floatx4 sv = *(const floatx4*)&S_in[(size_t)(b*256 + tid)*256 + l0 + j0];
            sv = th_d * sv;
#pragma unroll
            for (int w = 0; w < 8; ++w) {
                floatx4 kv = *(const floatx4*)&kWA[w*260 + l0 + j0];
                sv += uL[w] * kv;
            }
#pragma unroll
            for (int jj = 0; jj < 4; ++jj) {
                int row = j0 + jj;
                *(unsigned short*)(STb +
                    (((size_t)row*528 + 2*(size_t)tid) ^ (unsigned)((row & 8) << 1))) =
                    (unsigned short)f2bf(sv[jj]);
            }
        }
    }

    // ---- rowsq recurrence (exact, round-10 verified) + block norm reduce
    {
        float th_d = thv[tid];
        float cross = 0.f, quad = 0.f;
#pragma unroll
        for (int w = 0; w < 8; ++w) {
            cross += uL[w] * qv[w*256 + tid];   // own column, self-written
            float kk = 0.f;
#pragma unroll
            for (int w2 = 0; w2 < 8; ++w2) kk += Kl[w*8 + w2] * uL[w2];
            quad += uL[w] * kk;
        }
        float rq = th_d*th_d*rowsq_in[b*256 + tid] + 2.f*th_d*cross + quad;
        if (rem == 0) rowsq_out[b*256 + tid] = rq;
        float sum = rq;
#pragma unroll
        for (int off = 32; off; off >>= 1) sum += __shfl_xor(sum, off);
        if (lane == 0) red[wid] = sum;
    }
    __syncthreads();   // qv, STb, red ready

    // ---- c = theta.q + 0.5 K u
#pragma unroll
    for (int qq = 0; qq < 8; ++qq) {
        int idx = qq*256 + tid;
        int w = idx >> 8, e = idx & 255;
        float sv = thv[e] * qv[w*256 + e];
#pragma unroll
        for (int w2 = 0; w2 < 8; ++w2)
            sv += 0.5f * Kl[w*8 + w2] * uv[w2*256 + e];
        cv[w*256 + e] = sv;
    }
    __syncthreads();   // cv ready

    // ---- T update in regs (A-frag layout) from Tin; write Tout if s==0
    floatx4 T_reg[16];
    {
        const float* Trow = &Tin[(size_t)(b*256 + i0 + wid*16 + lme)*256];
        int i = i0 + wid*16 + lme;
        float thi = thv[i];
        float ui8[8], ci8[8];
#pragma unroll
        for (int w = 0; w < 8; ++w) { ui8[w] = uv[w*256 + i]; ci8[w] = cv[w*256 + i]; }
#pragma unroll
        for (int kc = 0; kc < 8; ++kc) {
            int k0 = kc*32 + hi*8;
            floatx4 t0 = *(const floatx4*)&Trow[k0];
            floatx4 t1 = *(const floatx4*)&Trow[k0 + 4];
            floatx4 th0 = *(const floatx4*)&thv[k0];
            floatx4 th1 = *(const floatx4*)&thv[k0 + 4];
            t0 = (thi * th0) * t0;
            t1 = (thi * th1) * t1;
#pragma unroll
            for (int w = 0; w < 8; ++w) {
                floatx4 uk0 = *(const floatx4*)&uv[w*256 + k0];
                floatx4 uk1 = *(const floatx4*)&uv[w*256 + k0 + 4];
                floatx4 ck0 = *(const floatx4*)&cv[w*256 + k0];
                floatx4 ck1 = *(const floatx4*)&cv[w*256 + k0 + 4];
                t0 += ui8[w]*ck0 + ci8[w]*uk0;
                t1 += ui8[w]*ck1 + ci8[w]*uk1;
            }
            T_reg[kc*2+0] = t0;
            T_reg[kc*2+1] = t1;
        }
        if (s == 0) {
            float* Torow = &Tout[(size_t)(b*256 + i0 + wid*16 + lme)*256];
#pragma unroll
            for (int kc = 0; kc < 8; ++kc) {
                *(floatx4*)&Torow[kc*32 + hi*8]     = T_reg[kc*2+0];
                *(floatx4*)&Torow[kc*32 + hi*8 + 4] = T_reg[kc*2+1];
            }
        }
    }

    // ---- MFMA TS tile
    floatx4 acc[4];
#pragma unroll
    for (int lt = 0; lt < 4; ++lt) acc[lt] = (floatx4){0.f,0.f,0.f,0.f};
#pragma unroll
    for (int kc = 0; kc < 8; ++kc) {
        BF8 ua; ua.u[0] = packbf4(T_reg[kc*2]); ua.u[1] = packbf4(T_reg[kc*2+1]);
        int kbyte = kc*64 + hi*16;
#pragma unroll
        for (int lt = 0; lt < 4; ++lt) {
            int row = lt*16 + lme;
            short8 bf = *(const short8*)(STb +
                (((size_t)row*528 + kbyte) ^ (unsigned)((row & 8) << 1)));
            acc[lt] = __builtin_amdgcn_mfma_f32_16x16x32_bf16(ua.s8, bf, acc[lt], 0,0,0);
        }
    }

    // ---- NS, M update (in place), y atomic, errp(t+1)
    {
        float nsq = 0.f;
#pragma unroll
        for (int q = 0; q < 16; ++q) nsq += red[q];
        float nrm = sqrtf(nsq) + 1e-7f;
        float inv_n = 1.f / nrm;
        float w1 = 1.5f * inv_n;
        float w3 = 0.5f * inv_n * inv_n * inv_n;
        float alv[4], etv[4], kvr[4], M_reg[16];
#pragma unroll
        for (int g = 0; g < 4; ++g) {
            alv[g] = alphaB[(size_t)(b*Ln + t)*Dn + ibr + g];
            etv[g] = etaB[(size_t)(b*Ln + t)*Dn + ibr + g];
        }
#pragma unroll
        for (int lt = 0; lt < 4; ++lt) kvr[lt] = kWA[7*260 + l0 + lt*16 + lme];
#pragma unroll
        for (int lt = 0; lt < 4; ++lt)
#pragma unroll
            for (int g = 0; g < 4; ++g)
                M_reg[lt*4+g] = Mg[(size_t)(b*256 + ibr + g)*256 + l0 + lt*16 + lme];
        float py[4] = {0.f,0.f,0.f,0.f};
#pragma unroll
        for (int lt = 0; lt < 4; ++lt)
#pragma unroll
            for (int g = 0; g < 4; ++g) {
                int l_loc = lt*16 + lme;
                unsigned short sb = *(const unsigned short*)(STb +
                    (((size_t)l_loc*528 + (size_t)(ibr + g)*2) ^ (unsigned)((l_loc & 8) << 1)));
                float s_il = __uint_as_float(((unsigned)sb) << 16);
                float ns = w1 * s_il - w3 * acc[lt][g];
                float mn = alv[g] * M_reg[lt*4+g] - etv[g] * ns;
                M_reg[lt*4+g] = mn;
                py[g] += mn * kvr[lt];
                Mg[(size_t)(b*256 + ibr + g)*256 + l0 + l_loc] = mn;
            }
#pragma unroll
        for (int g = 0; g < 4; ++g) {
            py[g] += __shfl_xor(py[g], 1); py[g] += __shfl_xor(py[g], 2);
            py[g] += __shfl_xor(py[g], 4); py[g] += __shfl_xor(py[g], 8);
            if (lme == 0) atomicAdd(&ys[(size_t)(b*Ln + t)*Dn + ibr + g], py[g]);
        }
        if (t < Ln - 1) {
            const int p2 = (t + 1) & 1;
#pragma unroll
            for (int w = 0; w < 8; ++w) {
                float pd[4] = {0.f,0.f,0.f,0.f};
#pragma unroll
                for (int lt = 0; lt < 4; ++lt) {
                    float kv2 = kW2[w*256 + l0 + lt*16 + lme];
#pragma unroll
                    for (int g = 0; g < 4; ++g) pd[g] += M_reg[lt*4+g] * kv2;
                }
#pragma unroll
                for (int g = 0; g < 4; ++g) {
                    pd[g] += __shfl_xor(pd[g], 1); pd[g] += __shfl_xor(pd[g], 2);
                    pd[g] += __shfl_xor(pd[g], 4); pd[g] += __shfl_xor(pd[g], 8);
                }
                if (lme == 0)
#pragma unroll
                    for (int g = 0; g < 4; ++g)
                        errp[(size_t)((s*2 + p2)*4 + b)*2048 + w*256 + ibr + g] = pd[g];
            }
        }
    }
}

// -------------------------------------------------------------------------
extern "C" void kernel_launch(void* const* d_in, const int* in_sizes, int n_in,
                              void* d_out, int out_size, void* d_ws, size_t ws_size,
                              hipStream_t stream)
{
    const float* x       = (const float*)d_in[0];
    const float* k_al    = (const float*)d_in[1];
    const float* v       = (const float*)d_in[2];
    const float* M_prev  = (const float*)d_in[3];
    const float* S_prev  = (const float*)d_in[4];
    const float* poly    = (const float*)d_in[5];
    const float* alpha_W = (const float*)d_in[6];
    const float* alpha_b = (const float*)d_in[7];
    const float* eta_W   = (const float*)d_in[8];
    const float* eta_b   = (const float*)d_in[9];
    const float* theta_W = (const float*)d_in[10];
    const float* theta_b = (const float*)d_in[11];
    const float* gamma_W = (const float*)d_in[12];
    const float* gamma_b = (const float*)d_in[13];
    const float* out_W   = (const float*)d_in[14];
    const float* out_b   = (const float*)d_in[15];

    float* ws = (float*)d_ws;
    float* kphi    = ws;                    // 262144
    float* alphaB  = kphi   + BLD;          // 262144
    float* etaB    = alphaB + BLD;          // 262144
    float* thetaB  = etaB   + BLD;          // 262144
    float* gammaB  = thetaB + BLD;          // 1024
    float* Kall    = gammaB + Bn*Ln;        // 65536
    float* S1      = Kall   + Bn*Ln*64;     // 262144 (parity-1 S; parity-0 = outS)
    float* errp    = S1     + BDD;          // 65536 (4 slots x 2 parity)
    float* rowsq0b = errp   + 65536;        // 1024
    float* rowsq1b = rowsq0b + 1024;        // 1024
    float* ysb     = rowsq1b + 1024;        // 262144
    float* Tg0     = ysb    + BLD;          // 262144
    float* Tg1     = Tg0    + BDD;          // 262144
    // total ~2.23M floats ~ 8.9 MB (< 9.5 MB proven round 9)

    float* out_y = (float*)d_out;           // [B,L,D]
    float* outM  = out_y + BLD;             // [B,D,D] M in place
    float* outS  = outM + BDD;              // [B,D,D] S parity-0 (final lands here)

    // precompute
    hipLaunchKernelGGL(kphi_gamma_kernel, dim3(256), dim3(256), 0, stream,
                       k_al, x, poly, gamma_W, gamma_b, kphi, gammaB);
    hipLaunchKernelGGL((gemm_act_kernel<1>), dim3(32, 4), dim3(256), 0, stream,
                       x, alpha_W, alpha_b, alphaB);
    hipLaunchKernelGGL((gemm_act_kernel<2>), dim3(32, 4), dim3(256), 0, stream,
                       x, eta_W, eta_b, etaB);
    hipLaunchKernelGGL((gemm_act_kernel<1>), dim3(32, 4), dim3(256), 0, stream,
                       x, theta_W, theta_b, thetaB);
    hipLaunchKernelGGL(kgram_kernel, dim3(Ln, Bn), dim3(64), 0, stream,
                       kphi, Kall);
    hipLaunchKernelGGL(prologue_kernel, dim3(256), dim3(256), 0, stream,
                       M_prev, S_prev, outM, outS, ysb, errp);
    hipLaunchKernelGGL(tinit_kernel, dim3(64), dim3(256), 0, stream,
                       S_prev, Tg0);
    hipLaunchKernelGGL(err0_kernel, dim3(64), dim3(256), 0, stream,
                       kphi, M_prev, S_prev, errp, rowsq0b);

    // ONE kernel per step; kernel boundaries provide all sync.
    // Parity: step t reads {S,T,rowsq,errp}[t&1], writes parity (t+1)&1.
    for (int t = 0; t < Ln; ++t) {
        float* S_in   = (t & 1) ? S1 : outS;
        float* S_out  = (t & 1) ? outS : S1;
        float* Tin    = (t & 1) ? Tg1 : Tg0;
        float* Tout   = (t & 1) ? Tg0 : Tg1;
        float* rq_in  = (t & 1) ? rowsq1b : rowsq0b;
        float* rq_out = (t & 1) ? rowsq0b : rowsq1b;
        hipLaunchKernelGGL(step_kernel, dim3(64), dim3(256), 0, stream,
                           kphi, v, gammaB, alphaB, etaB, thetaB, Kall,
                           S_in, S_out, Tin, Tout, rq_in, rq_out,
                           errp, outM, ysb, t);
    }

    // out projection
    hipLaunchKernelGGL((gemm_act_kernel<0>), dim3(32, 4), dim3(256), 0, stream,
                       ysb, out_W, out_b, out_y);
}